// Round 7
// baseline (88.904 us; speedup 1.0000x reference)
//
#include <hip/hip_runtime.h>

// Problem constants (fixed by reference setup_inputs)
constexpr int B = 4, N = 16384, Q = 4096, C = 64, S = 32;
constexpr int TS = 67;            // LDS tile row stride (floats); odd => <=2-way banks
constexpr int TGRID = B * (N / 64);   // 1024 transpose-role blocks
constexpr int QBLKS = (B * Q) / 4;    // 4096 query/group blocks (4 waves each)

typedef float f32x4 __attribute__((ext_vector_type(4)));

// ---------------------------------------------------------------------------
// Kernel 1 "prep": two roles selected by blockIdx.
//  role T (blocks [0,1024)): transpose features (B,C,N)->(B,N,C) into ws
//    with device-scope (sc0 sc1) dwordx4 stores (land at coherence point).
//  role A (blocks [1024,5120)): ball query, one wave per query.
//    Membership decided in f32 with a +-4e-6 band around 0.04f (f32 d2 error
//    <= ~3e-8: 100x margin); borderline lanes fall back to the f64 formula
//    proven bit-exact vs the harness reference. Writes grouped_xyz (out0)
//    directly (idx is local, s_xyz is cache-hot) and padded idx (u16, agent).
// ---------------------------------------------------------------------------
__global__ __launch_bounds__(256) void prep(const float* __restrict__ q_xyz,
                                            const float* __restrict__ s_xyz,
                                            const float* __restrict__ f,
                                            float* __restrict__ ft,
                                            unsigned short* __restrict__ idxb,
                                            float* __restrict__ out) {
    const int t = threadIdx.x;
    if ((int)blockIdx.x < TGRID) {
        // ---- transpose role ----
        __shared__ float tile[64 * 65];
        const int b  = blockIdx.x >> 8;          // N/64 = 256 blocks per batch
        const int n0 = (blockIdx.x & 255) * 64;
        const int nl = t & 63;
        const int cl = t >> 6;
        const float* fb = f + (size_t)b * C * N;
#pragma unroll
        for (int i = 0; i < 16; ++i) {
            const int c = i * 4 + cl;
            tile[c * 65 + nl] = fb[(size_t)c * N + n0 + nl];   // 256B coalesced per c
        }
        __syncthreads();
        float* ftb = ft + ((size_t)b * N + n0) * C;
        const int l15 = t & 15;
        const int nw  = t >> 4;                   // 0..15
#pragma unroll
        for (int it = 0; it < 4; ++it) {
            const int n = it * 16 + nw;
            f32x4 v;
#pragma unroll
            for (int k = 0; k < 4; ++k) v[k] = tile[(4 * l15 + k) * 65 + n];
            float* p = ftb + (size_t)n * C + 4 * l15;
            asm volatile("global_store_dwordx4 %0, %1, off sc0 sc1"
                         :: "v"(p), "v"(v) : "memory");
        }
    } else {
        // ---- query role: one wave per query ----
        __shared__ int idx_s[4][S];
        const int lane = t & 63;
        const int wid  = t >> 6;
        const int gq   = ((int)blockIdx.x - TGRID) * 4 + wid;   // 0..B*Q-1
        const int b    = gq >> 12;                              // Q = 4096
        const int q    = gq & (Q - 1);
        const float* qp = q_xyz + (size_t)gq * 3;
        const float qxf = qp[0], qyf = qp[1], qzf = qp[2];
        const double qxd = (double)qxf, qyd = (double)qyf, qzd = (double)qzf;
        const double R2D = 0.2 * 0.2;   // IEEE double = python's radius*radius
        const float R2F = 0.04f, EPS = 4e-6f;
        const float* sb = s_xyz + (size_t)b * N * 3;

        int cnt = 0;                                            // wave-uniform
        float sx = sb[lane * 3 + 0], sy = sb[lane * 3 + 1], sz = sb[lane * 3 + 2];
        for (int base = 0; base < N && cnt < S; base += 64) {
            float nx = sx, ny = sy, nz = sz;
            if (base + 64 < N) {                 // prefetch next chunk
                const int nn = (base + 64 + lane) * 3;
                nx = sb[nn + 0]; ny = sb[nn + 1]; nz = sb[nn + 2];
            }
            const float dxf = sx - qxf, dyf = sy - qyf, dzf = sz - qzf;
            const float d2f = dxf * dxf + dyf * dyf + dzf * dzf;
            bool in = d2f < R2F - EPS;                       // definitely inside
            const bool border = (!in) && (d2f <= R2F + EPS); // needs exact decision
            if (__any(border)) {
                if (border) {
                    const double dx = (double)sx - qxd;
                    const double dy = (double)sy - qyd;
                    const double dz = (double)sz - qzd;
                    in = (dx * dx + dy * dy + dz * dz) < R2D;   // exact f64
                }
            }
            const unsigned long long m = __ballot(in);
            if (in) {
                const int pos = cnt + __popcll(m & ((1ull << lane) - 1ull));
                if (pos < S) idx_s[wid][pos] = base + lane;
            }
            cnt += __popcll(m);
            sx = nx; sy = ny; sz = nz;
        }
        if (cnt > S) cnt = S;
        const int idx0 = (cnt > 0) ? idx_s[wid][0] : 0;
        if (lane < S && lane >= cnt) idx_s[wid][lane] = idx0;  // pad (same wave)

        // grouped_xyz: (B,3,Q,S) = support[idx] - query (single f32 sub: exact)
        const float qc[3] = {qxf, qyf, qzf};
        for (int e = lane; e < 3 * S; e += 64) {
            const int c  = e >> 5;
            const int sI = e & 31;
            const int id = idx_s[wid][sI];
            out[(((size_t)b * 3 + c) * Q + q) * S + sI] = sb[id * 3 + c] - qc[c];
        }

        if (lane < S) {                       // padded idx -> ws (device-scope)
            __hip_atomic_store(&idxb[(size_t)gq * S + lane],
                               (unsigned short)idx_s[wid][lane],
                               __ATOMIC_RELAXED, __HIP_MEMORY_SCOPE_AGENT);
        }
    }
}

// ---------------------------------------------------------------------------
// Kernel 2 "group": pure feature gather+write, one wave per query, uniform.
// idx via agent u16 loads; ft via sc0 sc1 dwordx4 (bypass possibly-stale L2).
// Output via dwordx4 stores (4 per lane per 16-s pass).
// ---------------------------------------------------------------------------
__global__ __launch_bounds__(256) void group(const float* __restrict__ ft,
                                             const unsigned short* __restrict__ idxb,
                                             float* __restrict__ out) {
    __shared__ int   idx_s[4][S];
    __shared__ float tile[4][16 * TS];   // 16-row half-tile per wave (double pass)

    const int t    = threadIdx.x;
    const int lane = t & 63;
    const int wid  = t >> 6;
    const int gq   = blockIdx.x * 4 + wid;
    const int b    = gq >> 12;
    const int q    = gq & (Q - 1);

    if (lane < S) {
        const unsigned short v =
            __hip_atomic_load(&idxb[(size_t)gq * S + lane],
                              __ATOMIC_RELAXED, __HIP_MEMORY_SCOPE_AGENT);
        idx_s[wid][lane] = (int)v;
    }

    const int sub = lane >> 4;           // 0..3 : row-within-quad for gather
    const int cq  = (lane & 15) * 4;     // col start (floats) for gather
    const int a4  = lane & 3;            // s-quad within pass for output
    const int ch  = lane >> 2;           // 0..15 : c within 16-c group for output
    float* out1 = out + (size_t)B * 3 * Q * S;
    const float* ftb = ft + (size_t)b * N * C;

    // issue all 8 gather loads up-front (L3-coherent, bypass stale L2)
    f32x4 v[8];
#pragma unroll
    for (int j = 0; j < 8; ++j) {
        const int id = idx_s[wid][j * 4 + sub];
        const float* p = ftb + ((size_t)id << 6) + cq;
        asm volatile("global_load_dwordx4 %0, %1, off sc0 sc1"
                     : "=v"(v[j]) : "v"(p));
    }

    // ---- pass 0: s = 0..15 ----
    asm volatile("s_waitcnt vmcnt(4)" ::: "memory");   // loads 0..3 retired
    __builtin_amdgcn_sched_barrier(0);
#pragma unroll
    for (int j = 0; j < 4; ++j) {
        const int r = j * 4 + sub;
#pragma unroll
        for (int k = 0; k < 4; ++k)
            tile[wid][r * TS + cq + k] = v[j][k];
    }
#pragma unroll
    for (int i = 0; i < 4; ++i) {        // 4 dwordx4 stores: c = 16i+ch, s quad a4
        const int c = i * 16 + ch;
        f32x4 w;
#pragma unroll
        for (int k = 0; k < 4; ++k) w[k] = tile[wid][(4 * a4 + k) * TS + c];
        float* p = out1 + (((size_t)b * C + c) * Q + q) * S + 4 * a4;
        asm volatile("global_store_dwordx4 %0, %1, off"
                     :: "v"(p), "v"(w) : "memory");
    }

    // ---- pass 1: s = 16..31 ----
    // After the 4 stores above: outstanding tail = {L4..L7, 4 stores}; vmcnt(4)
    // with in-order retirement guarantees L4..L7 done (<=4 left = the stores).
    asm volatile("s_waitcnt vmcnt(4)" ::: "memory");
    __builtin_amdgcn_sched_barrier(0);
#pragma unroll
    for (int j = 0; j < 4; ++j) {
        const int r = j * 4 + sub;
#pragma unroll
        for (int k = 0; k < 4; ++k)
            tile[wid][r * TS + cq + k] = v[4 + j][k];
    }
#pragma unroll
    for (int i = 0; i < 4; ++i) {
        const int c = i * 16 + ch;
        f32x4 w;
#pragma unroll
        for (int k = 0; k < 4; ++k) w[k] = tile[wid][(4 * a4 + k) * TS + c];
        float* p = out1 + (((size_t)b * C + c) * Q + q) * S + 16 + 4 * a4;
        asm volatile("global_store_dwordx4 %0, %1, off"
                     :: "v"(p), "v"(w) : "memory");
    }
}

// ---------------------------------------------------------------------------
// Fallback (ws too small): fused single kernel, original feature layout.
// ---------------------------------------------------------------------------
__global__ __launch_bounds__(256) void ballgroup_fb(const float* __restrict__ q_xyz,
                                                    const float* __restrict__ s_xyz,
                                                    const float* __restrict__ feat,
                                                    float* __restrict__ out) {
    __shared__ int   idx_s[4][S];
    __shared__ float tile[4][16 * TS];
    const int t = threadIdx.x, lane = t & 63, wid = t >> 6;
    const int gq = blockIdx.x * 4 + wid;
    const int b = gq >> 12, q = gq & (Q - 1);
    const float* qp = q_xyz + (size_t)gq * 3;
    const double qxd = (double)qp[0], qyd = (double)qp[1], qzd = (double)qp[2];
    const double R2D = 0.2 * 0.2;
    const float* sb = s_xyz + (size_t)b * N * 3;
    int cnt = 0;
    for (int base = 0; base < N && cnt < S; base += 64) {
        const int n = base + lane;
        const double dx = (double)sb[n * 3 + 0] - qxd;
        const double dy = (double)sb[n * 3 + 1] - qyd;
        const double dz = (double)sb[n * 3 + 2] - qzd;
        const bool in = (dx * dx + dy * dy + dz * dz) < R2D;
        const unsigned long long m = __ballot(in);
        if (in) {
            const int pos = cnt + __popcll(m & ((1ull << lane) - 1ull));
            if (pos < S) idx_s[wid][pos] = n;
        }
        cnt += __popcll(m);
    }
    if (cnt > S) cnt = S;
    const int idx0 = (cnt > 0) ? idx_s[wid][0] : 0;
    if (lane < S && lane >= cnt) idx_s[wid][lane] = idx0;
    for (int e = lane; e < 3 * S; e += 64) {
        const int c = e >> 5, sI = e & 31;
        const int id = idx_s[wid][sI];
        out[(((size_t)b * 3 + c) * Q + q) * S + sI] = sb[id * 3 + c] - qp[c];
    }
    float* out1 = out + (size_t)B * 3 * Q * S;
    const int chi = lane >> 4, sI16 = lane & 15;
    const float* fb = feat + (size_t)b * C * N;
    for (int p = 0; p < 2; ++p) {
        for (int s2 = 0; s2 < 16; ++s2) {
            const int id = idx_s[wid][p * 16 + s2];
            tile[wid][s2 * TS + lane] = fb[(size_t)lane * N + id];
        }
#pragma unroll
        for (int i = 0; i < 16; ++i) {
            const int c = i * 4 + chi;
            out1[(((size_t)b * C + c) * Q + q) * S + p * 16 + sI16] =
                tile[wid][sI16 * TS + c];
        }
    }
}

extern "C" void kernel_launch(void* const* d_in, const int* in_sizes, int n_in,
                              void* d_out, int out_size, void* d_ws, size_t ws_size,
                              hipStream_t stream) {
    const float* q_xyz = (const float*)d_in[0];   // (B,Q,3)
    const float* s_xyz = (const float*)d_in[1];   // (B,N,3)
    const float* feat  = (const float*)d_in[2];   // (B,C,N)
    float* out = (float*)d_out;

    const size_t ftBytes  = (size_t)B * N * C * sizeof(float);          // 16 MB
    const size_t idxBytes = (size_t)B * Q * S * sizeof(unsigned short); // 1 MB
    if (ws_size >= ftBytes + idxBytes) {
        float* ft = (float*)d_ws;
        unsigned short* idxb = (unsigned short*)((char*)d_ws + ftBytes);
        prep<<<TGRID + QBLKS, 256, 0, stream>>>(q_xyz, s_xyz, feat, ft, idxb, out);
        group<<<QBLKS, 256, 0, stream>>>(ft, idxb, out);
    } else {
        ballgroup_fb<<<QBLKS, 256, 0, stream>>>(q_xyz, s_xyz, feat, out);
    }
}

// Round 8
// 86.257 us; speedup vs baseline: 1.0307x; 1.0307x over previous
//
#include <hip/hip_runtime.h>

// Problem constants (fixed by reference setup_inputs)
constexpr int B = 4, N = 16384, Q = 4096, C = 64, S = 32;
constexpr int TS = 67;            // LDS tile row stride (floats); odd => ~2-way banks
constexpr int TGRID = B * (N / 64);   // 1024 transpose-role blocks
constexpr int QBLKS = (B * Q) / 4;    // 4096 query/group blocks (4 waves each)

typedef float f32x4 __attribute__((ext_vector_type(4)));

// ---------------------------------------------------------------------------
// Kernel 1 "prep": two roles selected by blockIdx.
//  role T (blocks [0,1024)): transpose features (B,C,N)->(B,N,C) into ws
//    with device-scope (sc0 sc1) dwordx4 stores (land at coherence point).
//  role A (blocks [1024,5120)): ball query only (no out0 writes — round-7
//    post-mortem: they belong in group where they hide gather latency).
//    f32 band prefilter (err<=3e-8 vs 4e-6 band), f64 exact on borderline.
// ---------------------------------------------------------------------------
__global__ __launch_bounds__(256) void prep(const float* __restrict__ q_xyz,
                                            const float* __restrict__ s_xyz,
                                            const float* __restrict__ f,
                                            float* __restrict__ ft,
                                            unsigned short* __restrict__ idxb) {
    const int t = threadIdx.x;
    if ((int)blockIdx.x < TGRID) {
        // ---- transpose role ----
        __shared__ float tile[64 * 65];
        const int b  = blockIdx.x >> 8;          // N/64 = 256 blocks per batch
        const int n0 = (blockIdx.x & 255) * 64;
        const int nl = t & 63;
        const int cl = t >> 6;
        const float* fb = f + (size_t)b * C * N;
#pragma unroll
        for (int i = 0; i < 16; ++i) {
            const int c = i * 4 + cl;
            tile[c * 65 + nl] = fb[(size_t)c * N + n0 + nl];   // 256B coalesced per c
        }
        __syncthreads();
        float* ftb = ft + ((size_t)b * N + n0) * C;
        const int l15 = t & 15;
        const int nw  = t >> 4;                   // 0..15
#pragma unroll
        for (int it = 0; it < 4; ++it) {
            const int n = it * 16 + nw;
            f32x4 v;
#pragma unroll
            for (int k = 0; k < 4; ++k) v[k] = tile[(4 * l15 + k) * 65 + n];
            float* p = ftb + (size_t)n * C + 4 * l15;
            asm volatile("global_store_dwordx4 %0, %1, off sc0 sc1"
                         :: "v"(p), "v"(v) : "memory");
        }
    } else {
        // ---- query role: one wave per query ----
        __shared__ int idx_s[4][S];
        const int lane = t & 63;
        const int wid  = t >> 6;
        const int gq   = ((int)blockIdx.x - TGRID) * 4 + wid;   // 0..B*Q-1
        const int b    = gq >> 12;                              // Q = 4096
        const float* qp = q_xyz + (size_t)gq * 3;
        const float qxf = qp[0], qyf = qp[1], qzf = qp[2];
        const double qxd = (double)qxf, qyd = (double)qyf, qzd = (double)qzf;
        const double R2D = 0.2 * 0.2;   // IEEE double = python's radius*radius
        const float R2F = 0.04f, EPS = 4e-6f;
        const float* sb = s_xyz + (size_t)b * N * 3;

        int cnt = 0;                                            // wave-uniform
        float sx = sb[lane * 3 + 0], sy = sb[lane * 3 + 1], sz = sb[lane * 3 + 2];
        for (int base = 0; base < N && cnt < S; base += 64) {
            float nx = sx, ny = sy, nz = sz;
            if (base + 64 < N) {                 // prefetch next chunk
                const int nn = (base + 64 + lane) * 3;
                nx = sb[nn + 0]; ny = sb[nn + 1]; nz = sb[nn + 2];
            }
            const float dxf = sx - qxf, dyf = sy - qyf, dzf = sz - qzf;
            const float d2f = dxf * dxf + dyf * dyf + dzf * dzf;
            bool in = d2f < R2F - EPS;                       // definitely inside
            const bool border = (!in) && (d2f <= R2F + EPS); // needs exact decision
            if (__any(border)) {
                if (border) {
                    const double dx = (double)sx - qxd;
                    const double dy = (double)sy - qyd;
                    const double dz = (double)sz - qzd;
                    in = (dx * dx + dy * dy + dz * dz) < R2D;   // exact f64
                }
            }
            const unsigned long long m = __ballot(in);
            if (in) {
                const int pos = cnt + __popcll(m & ((1ull << lane) - 1ull));
                if (pos < S) idx_s[wid][pos] = base + lane;
            }
            cnt += __popcll(m);
            sx = nx; sy = ny; sz = nz;
        }
        if (cnt > S) cnt = S;
        const int idx0 = (cnt > 0) ? idx_s[wid][0] : 0;
        if (lane < S) {
            const int v = (lane < cnt) ? idx_s[wid][lane] : idx0;  // pad w/ first
            __hip_atomic_store(&idxb[(size_t)gq * S + lane], (unsigned short)v,
                               __ATOMIC_RELAXED, __HIP_MEMORY_SCOPE_AGENT);
        }
    }
}

// ---------------------------------------------------------------------------
// Kernel 2 "group": one wave per query, uniform. Issue 8 L3-coherent gather
// loads; hide their latency under the grouped_xyz computation+stores; drain
// with exactly-counted vmcnt (vmem retires in order; any compiler-issued
// sb/qp loads only make the waits stricter, never looser).
// ---------------------------------------------------------------------------
__global__ __launch_bounds__(256) void group(const float* __restrict__ q_xyz,
                                             const float* __restrict__ s_xyz,
                                             const float* __restrict__ ft,
                                             const unsigned short* __restrict__ idxb,
                                             float* __restrict__ out) {
    __shared__ int   idx_s[4][S];
    __shared__ float tile[4][16 * TS];   // 16-row half-tile per wave (double pass)

    const int t    = threadIdx.x;
    const int lane = t & 63;
    const int wid  = t >> 6;
    const int gq   = blockIdx.x * 4 + wid;
    const int b    = gq >> 12;
    const int q    = gq & (Q - 1);

    if (lane < S) {
        const unsigned short v =
            __hip_atomic_load(&idxb[(size_t)gq * S + lane],
                              __ATOMIC_RELAXED, __HIP_MEMORY_SCOPE_AGENT);
        idx_s[wid][lane] = (int)v;
    }

    const int sub = lane >> 4;           // 0..3 : row-within-quad for gather
    const int cq  = (lane & 15) * 4;     // col start (floats) for gather
    const int a4  = lane & 3;            // s-quad within pass for output
    const int ch  = lane >> 2;           // 0..15 : c within 16-c group for output
    float* out1 = out + (size_t)B * 3 * Q * S;
    const float* ftb = ft + (size_t)b * N * C;
    const float* sb  = s_xyz + (size_t)b * N * 3;
    const float* qp  = q_xyz + (size_t)gq * 3;

    // issue all 8 gather loads up-front (L3-coherent, bypass stale L2)
    f32x4 v[8];
#pragma unroll
    for (int j = 0; j < 8; ++j) {
        const int id = idx_s[wid][j * 4 + sub];
        const float* p = ftb + ((size_t)id << 6) + cq;
        asm volatile("global_load_dwordx4 %0, %1, off sc0 sc1"
                     : "=v"(v[j]) : "v"(p));
    }

    // grouped_xyz overlaps the gather latency (2 counted asm stores/wave):
    // e = lane and e = 64+lane(<96): c = e>>5, sI = e&31.
    {
        const int c0 = lane >> 5, s0 = lane & 31;
        const int id0 = idx_s[wid][s0];
        const float w0 = sb[id0 * 3 + c0] - qp[c0];
        float* p0 = out + (((size_t)b * 3 + c0) * Q + q) * S + s0;
        asm volatile("global_store_dword %0, %1, off" :: "v"(p0), "v"(w0) : "memory");
        float w1 = 0.0f;
        float* p1 = p0;
        if (lane < 32) {
            const int id1 = idx_s[wid][lane];
            w1 = sb[id1 * 3 + 2] - qp[2];
            p1 = out + (((size_t)b * 3 + 2) * Q + q) * S + lane;
        }
        if (lane < 32)   // wave-wide: issues once, exec-masked
            asm volatile("global_store_dword %0, %1, off" :: "v"(p1), "v"(w1) : "memory");
    }

    // ---- pass 0: s = 0..15 ----
    // Outstanding >= {L0..L7, xyz st x2}; vmcnt(6) retires oldest >=4 => L0..L3.
    asm volatile("s_waitcnt vmcnt(6)" ::: "memory");
    __builtin_amdgcn_sched_barrier(0);
#pragma unroll
    for (int j = 0; j < 4; ++j) {
        const int r = j * 4 + sub;
#pragma unroll
        for (int k = 0; k < 4; ++k)
            tile[wid][r * TS + cq + k] = v[j][k];
    }
#pragma unroll
    for (int i = 0; i < 4; ++i) {        // 4 dwordx4 stores: c = 16i+ch, s quad a4
        const int c = i * 16 + ch;
        f32x4 w;
#pragma unroll
        for (int k = 0; k < 4; ++k) w[k] = tile[wid][(4 * a4 + k) * TS + c];
        float* p = out1 + (((size_t)b * C + c) * Q + q) * S + 4 * a4;
        asm volatile("global_store_dwordx4 %0, %1, off" :: "v"(p), "v"(w) : "memory");
    }

    // ---- pass 1: s = 16..31 ----
    // Outstanding <= {L4..L7, xyz st x2, out st x4}; vmcnt(4) leaves the 4
    // youngest (output stores) in flight, guarantees L4..L7 retired.
    asm volatile("s_waitcnt vmcnt(4)" ::: "memory");
    __builtin_amdgcn_sched_barrier(0);
#pragma unroll
    for (int j = 0; j < 4; ++j) {
        const int r = j * 4 + sub;
#pragma unroll
        for (int k = 0; k < 4; ++k)
            tile[wid][r * TS + cq + k] = v[4 + j][k];
    }
#pragma unroll
    for (int i = 0; i < 4; ++i) {
        const int c = i * 16 + ch;
        f32x4 w;
#pragma unroll
        for (int k = 0; k < 4; ++k) w[k] = tile[wid][(4 * a4 + k) * TS + c];
        float* p = out1 + (((size_t)b * C + c) * Q + q) * S + 16 + 4 * a4;
        asm volatile("global_store_dwordx4 %0, %1, off" :: "v"(p), "v"(w) : "memory");
    }
}

// ---------------------------------------------------------------------------
// Fallback (ws too small): fused single kernel, original feature layout.
// ---------------------------------------------------------------------------
__global__ __launch_bounds__(256) void ballgroup_fb(const float* __restrict__ q_xyz,
                                                    const float* __restrict__ s_xyz,
                                                    const float* __restrict__ feat,
                                                    float* __restrict__ out) {
    __shared__ int   idx_s[4][S];
    __shared__ float tile[4][16 * TS];
    const int t = threadIdx.x, lane = t & 63, wid = t >> 6;
    const int gq = blockIdx.x * 4 + wid;
    const int b = gq >> 12, q = gq & (Q - 1);
    const float* qp = q_xyz + (size_t)gq * 3;
    const double qxd = (double)qp[0], qyd = (double)qp[1], qzd = (double)qp[2];
    const double R2D = 0.2 * 0.2;
    const float* sb = s_xyz + (size_t)b * N * 3;
    int cnt = 0;
    for (int base = 0; base < N && cnt < S; base += 64) {
        const int n = base + lane;
        const double dx = (double)sb[n * 3 + 0] - qxd;
        const double dy = (double)sb[n * 3 + 1] - qyd;
        const double dz = (double)sb[n * 3 + 2] - qzd;
        const bool in = (dx * dx + dy * dy + dz * dz) < R2D;
        const unsigned long long m = __ballot(in);
        if (in) {
            const int pos = cnt + __popcll(m & ((1ull << lane) - 1ull));
            if (pos < S) idx_s[wid][pos] = n;
        }
        cnt += __popcll(m);
    }
    if (cnt > S) cnt = S;
    const int idx0 = (cnt > 0) ? idx_s[wid][0] : 0;
    if (lane < S && lane >= cnt) idx_s[wid][lane] = idx0;
    for (int e = lane; e < 3 * S; e += 64) {
        const int c = e >> 5, sI = e & 31;
        const int id = idx_s[wid][sI];
        out[(((size_t)b * 3 + c) * Q + q) * S + sI] = sb[id * 3 + c] - qp[c];
    }
    float* out1 = out + (size_t)B * 3 * Q * S;
    const int chi = lane >> 4, sI16 = lane & 15;
    const float* fb = feat + (size_t)b * C * N;
    for (int p = 0; p < 2; ++p) {
        for (int s2 = 0; s2 < 16; ++s2) {
            const int id = idx_s[wid][p * 16 + s2];
            tile[wid][s2 * TS + lane] = fb[(size_t)lane * N + id];
        }
#pragma unroll
        for (int i = 0; i < 16; ++i) {
            const int c = i * 4 + chi;
            out1[(((size_t)b * C + c) * Q + q) * S + p * 16 + sI16] =
                tile[wid][sI16 * TS + c];
        }
    }
}

extern "C" void kernel_launch(void* const* d_in, const int* in_sizes, int n_in,
                              void* d_out, int out_size, void* d_ws, size_t ws_size,
                              hipStream_t stream) {
    const float* q_xyz = (const float*)d_in[0];   // (B,Q,3)
    const float* s_xyz = (const float*)d_in[1];   // (B,N,3)
    const float* feat  = (const float*)d_in[2];   // (B,C,N)
    float* out = (float*)d_out;

    const size_t ftBytes  = (size_t)B * N * C * sizeof(float);          // 16 MB
    const size_t idxBytes = (size_t)B * Q * S * sizeof(unsigned short); // 1 MB
    if (ws_size >= ftBytes + idxBytes) {
        float* ft = (float*)d_ws;
        unsigned short* idxb = (unsigned short*)((char*)d_ws + ftBytes);
        prep<<<TGRID + QBLKS, 256, 0, stream>>>(q_xyz, s_xyz, feat, ft, idxb);
        group<<<QBLKS, 256, 0, stream>>>(q_xyz, s_xyz, ft, idxb, out);
    } else {
        ballgroup_fb<<<QBLKS, 256, 0, stream>>>(q_xyz, s_xyz, feat, out);
    }
}

// Round 9
// 64.527 us; speedup vs baseline: 1.3778x; 1.3367x over previous
//
#include <hip/hip_runtime.h>

// Problem constants (fixed by reference setup_inputs)
constexpr int B = 4, N = 16384, Q = 4096, C = 64, S = 32;
constexpr int TS = 67;              // LDS tile row stride (floats); odd => ~2-way banks
constexpr int QBLKS = (B * Q) / 4;  // 4096 scan+gather blocks (4 waves each)

typedef float f32x4 __attribute__((ext_vector_type(4)));

// ---------------------------------------------------------------------------
// Kernel 1: transpose features (B,C,N) -> (B,N,C) into ws with device-scope
// (sc0 sc1) dwordx4 stores (land at the coherence point; per-XCD L2s are not
// cross-coherent and graph replay does not re-clean them — proven in r2/r3).
// ---------------------------------------------------------------------------
__global__ __launch_bounds__(256) void transpose_feat(const float* __restrict__ f,
                                                      float* __restrict__ ft) {
    __shared__ float tile[64 * 65];
    const int b  = blockIdx.x >> 8;           // N/64 = 256 blocks per batch
    const int n0 = (blockIdx.x & 255) * 64;
    const int t  = threadIdx.x;
    const int nl = t & 63;
    const int cl = t >> 6;
    const float* fb = f + (size_t)b * C * N;
#pragma unroll
    for (int i = 0; i < 16; ++i) {
        const int c = i * 4 + cl;
        tile[c * 65 + nl] = fb[(size_t)c * N + n0 + nl];   // 256B coalesced per c
    }
    __syncthreads();
    float* ftb = ft + ((size_t)b * N + n0) * C;
    const int l15 = t & 15;
    const int nw  = t >> 4;                    // 0..15
#pragma unroll
    for (int it = 0; it < 4; ++it) {
        const int n = it * 16 + nw;
        f32x4 v;
#pragma unroll
        for (int k = 0; k < 4; ++k) v[k] = tile[(4 * l15 + k) * 65 + n];
        float* p = ftb + (size_t)n * C + 4 * l15;
        asm volatile("global_store_dwordx4 %0, %1, off sc0 sc1"
                     :: "v"(p), "v"(v) : "memory");
    }
}

// ---------------------------------------------------------------------------
// Kernel 2 "sg": fused scan+gather, one wave per query, no cross-wave coupling
// (no __syncthreads, per-wave LDS). Waves with short scans start streaming
// gathers/stores while long-scan waves still compute -> scan latency hides
// under the bandwidth phase instead of serializing two dispatches.
// ---------------------------------------------------------------------------
__global__ __launch_bounds__(256) void sg(const float* __restrict__ q_xyz,
                                          const float* __restrict__ s_xyz,
                                          const float* __restrict__ ft,
                                          float* __restrict__ out) {
    __shared__ int   idx_s[4][S];
    __shared__ float tile[4][16 * TS];   // 16-row half-tile per wave (double pass)

    const int t    = threadIdx.x;
    const int lane = t & 63;
    const int wid  = t >> 6;
    const int gq   = blockIdx.x * 4 + wid;   // 0..B*Q-1
    const int b    = gq >> 12;               // Q = 4096
    const int q    = gq & (Q - 1);

    const float* qp = q_xyz + (size_t)gq * 3;
    const float qxf = qp[0], qyf = qp[1], qzf = qp[2];
    const double qxd = (double)qxf, qyd = (double)qyf, qzd = (double)qzf;
    const double R2D = 0.2 * 0.2;   // IEEE double = python's radius*radius
    const float R2F = 0.04f, EPS = 4e-6f;
    const float* sb = s_xyz + (size_t)b * N * 3;

    // ---- phase 1: ordered ballot ball-query (f32 prefilter, f64 border) ----
    int cnt = 0;                                            // wave-uniform
    float sx = sb[lane * 3 + 0], sy = sb[lane * 3 + 1], sz = sb[lane * 3 + 2];
    for (int base = 0; base < N && cnt < S; base += 64) {
        float nx = sx, ny = sy, nz = sz;
        if (base + 64 < N) {                 // prefetch next chunk
            const int nn = (base + 64 + lane) * 3;
            nx = sb[nn + 0]; ny = sb[nn + 1]; nz = sb[nn + 2];
        }
        const float dxf = sx - qxf, dyf = sy - qyf, dzf = sz - qzf;
        const float d2f = dxf * dxf + dyf * dyf + dzf * dzf;
        bool in = d2f < R2F - EPS;                       // definitely inside
        const bool border = (!in) && (d2f <= R2F + EPS); // needs exact decision
        if (__any(border)) {
            if (border) {
                const double dx = (double)sx - qxd;
                const double dy = (double)sy - qyd;
                const double dz = (double)sz - qzd;
                in = (dx * dx + dy * dy + dz * dz) < R2D;   // exact f64 (proven)
            }
        }
        const unsigned long long m = __ballot(in);
        if (in) {
            const int pos = cnt + __popcll(m & ((1ull << lane) - 1ull));
            if (pos < S) idx_s[wid][pos] = base + lane;
        }
        cnt += __popcll(m);
        sx = nx; sy = ny; sz = nz;
    }
    if (cnt > S) cnt = S;
    const int idx0 = (cnt > 0) ? idx_s[wid][0] : 0;
    if (lane < S && lane >= cnt) idx_s[wid][lane] = idx0;  // pad (same wave)

    // ---- phase 2: gather + write (starts immediately per wave) ----
    const int sub = lane >> 4;           // 0..3 : row-within-quad for gather
    const int cq  = (lane & 15) * 4;     // col start (floats) for gather
    const int a4  = lane & 3;            // s-quad within pass for output
    const int ch  = lane >> 2;           // 0..15 : c within 16-c group for output
    float* out1 = out + (size_t)B * 3 * Q * S;
    const float* ftb = ft + (size_t)b * N * C;

    // issue all 8 gather loads up-front (L3-coherent, bypass stale L2) G0..G7
    f32x4 v[8];
#pragma unroll
    for (int j = 0; j < 8; ++j) {
        const int id = idx_s[wid][j * 4 + sub];
        const float* p = ftb + ((size_t)id << 6) + cq;
        asm volatile("global_load_dwordx4 %0, %1, off sc0 sc1"
                     : "=v"(v[j]) : "v"(p));
    }

    // grouped_xyz overlaps gather latency: 2 counted asm stores S0,S1
    {
        const int c0 = lane >> 5, s0 = lane & 31;
        const int id0 = idx_s[wid][s0];
        const float w0 = sb[id0 * 3 + c0] - qp[c0];
        float* p0 = out + (((size_t)b * 3 + c0) * Q + q) * S + s0;
        asm volatile("global_store_dword %0, %1, off" :: "v"(p0), "v"(w0) : "memory");
        float w1 = 0.0f;
        float* p1 = p0;
        if (lane < 32) {
            const int id1 = idx_s[wid][lane];
            w1 = sb[id1 * 3 + 2] - qp[2];
            p1 = out + (((size_t)b * 3 + 2) * Q + q) * S + lane;
        }
        if (lane < 32)
            asm volatile("global_store_dword %0, %1, off" :: "v"(p1), "v"(w1) : "memory");
    }

    // ---- pass 0: s = 0..15 ----
    // In-order retirement: >=6 vmem ops are younger than G3 (G4..G7,S0,S1), so
    // after vmcnt(6) the <=6 remaining are all younger than G3 => G0..G3 done.
    asm volatile("s_waitcnt vmcnt(6)" ::: "memory");
    __builtin_amdgcn_sched_barrier(0);
#pragma unroll
    for (int j = 0; j < 4; ++j) {
        const int r = j * 4 + sub;
#pragma unroll
        for (int k = 0; k < 4; ++k)
            tile[wid][r * TS + cq + k] = v[j][k];
    }
#pragma unroll
    for (int i = 0; i < 4; ++i) {        // O0..O3: c = 16i+ch, s quad a4
        const int c = i * 16 + ch;
        f32x4 w;
#pragma unroll
        for (int k = 0; k < 4; ++k) w[k] = tile[wid][(4 * a4 + k) * TS + c];
        float* p = out1 + (((size_t)b * C + c) * Q + q) * S + 4 * a4;
        asm volatile("global_store_dwordx4 %0, %1, off" :: "v"(p), "v"(w) : "memory");
    }

    // ---- pass 1: s = 16..31 ----
    // >=4 ops younger than G7 (O0..O3) => vmcnt(4) retires G4..G7, never waits
    // on the 4 youngest output stores.
    asm volatile("s_waitcnt vmcnt(4)" ::: "memory");
    __builtin_amdgcn_sched_barrier(0);
#pragma unroll
    for (int j = 0; j < 4; ++j) {
        const int r = j * 4 + sub;
#pragma unroll
        for (int k = 0; k < 4; ++k)
            tile[wid][r * TS + cq + k] = v[4 + j][k];
    }
#pragma unroll
    for (int i = 0; i < 4; ++i) {
        const int c = i * 16 + ch;
        f32x4 w;
#pragma unroll
        for (int k = 0; k < 4; ++k) w[k] = tile[wid][(4 * a4 + k) * TS + c];
        float* p = out1 + (((size_t)b * C + c) * Q + q) * S + 16 + 4 * a4;
        asm volatile("global_store_dwordx4 %0, %1, off" :: "v"(p), "v"(w) : "memory");
    }
}

// ---------------------------------------------------------------------------
// Fallback (ws too small): fused single kernel, original feature layout.
// ---------------------------------------------------------------------------
__global__ __launch_bounds__(256) void ballgroup_fb(const float* __restrict__ q_xyz,
                                                    const float* __restrict__ s_xyz,
                                                    const float* __restrict__ feat,
                                                    float* __restrict__ out) {
    __shared__ int   idx_s[4][S];
    __shared__ float tile[4][16 * TS];
    const int t = threadIdx.x, lane = t & 63, wid = t >> 6;
    const int gq = blockIdx.x * 4 + wid;
    const int b = gq >> 12, q = gq & (Q - 1);
    const float* qp = q_xyz + (size_t)gq * 3;
    const double qxd = (double)qp[0], qyd = (double)qp[1], qzd = (double)qp[2];
    const double R2D = 0.2 * 0.2;
    const float* sb = s_xyz + (size_t)b * N * 3;
    int cnt = 0;
    for (int base = 0; base < N && cnt < S; base += 64) {
        const int n = base + lane;
        const double dx = (double)sb[n * 3 + 0] - qxd;
        const double dy = (double)sb[n * 3 + 1] - qyd;
        const double dz = (double)sb[n * 3 + 2] - qzd;
        const bool in = (dx * dx + dy * dy + dz * dz) < R2D;
        const unsigned long long m = __ballot(in);
        if (in) {
            const int pos = cnt + __popcll(m & ((1ull << lane) - 1ull));
            if (pos < S) idx_s[wid][pos] = n;
        }
        cnt += __popcll(m);
    }
    if (cnt > S) cnt = S;
    const int idx0 = (cnt > 0) ? idx_s[wid][0] : 0;
    if (lane < S && lane >= cnt) idx_s[wid][lane] = idx0;
    for (int e = lane; e < 3 * S; e += 64) {
        const int c = e >> 5, sI = e & 31;
        const int id = idx_s[wid][sI];
        out[(((size_t)b * 3 + c) * Q + q) * S + sI] = sb[id * 3 + c] - qp[c];
    }
    float* out1 = out + (size_t)B * 3 * Q * S;
    const int chi = lane >> 4, sI16 = lane & 15;
    const float* fb = feat + (size_t)b * C * N;
    for (int p = 0; p < 2; ++p) {
        for (int s2 = 0; s2 < 16; ++s2) {
            const int id = idx_s[wid][p * 16 + s2];
            tile[wid][s2 * TS + lane] = fb[(size_t)lane * N + id];
        }
#pragma unroll
        for (int i = 0; i < 16; ++i) {
            const int c = i * 4 + chi;
            out1[(((size_t)b * C + c) * Q + q) * S + p * 16 + sI16] =
                tile[wid][sI16 * TS + c];
        }
    }
}

extern "C" void kernel_launch(void* const* d_in, const int* in_sizes, int n_in,
                              void* d_out, int out_size, void* d_ws, size_t ws_size,
                              hipStream_t stream) {
    const float* q_xyz = (const float*)d_in[0];   // (B,Q,3)
    const float* s_xyz = (const float*)d_in[1];   // (B,N,3)
    const float* feat  = (const float*)d_in[2];   // (B,C,N)
    float* out = (float*)d_out;

    const size_t ftBytes = (size_t)B * N * C * sizeof(float);   // 16 MB
    if (ws_size >= ftBytes) {
        float* ft = (float*)d_ws;
        transpose_feat<<<B * (N / 64), 256, 0, stream>>>(feat, ft);
        sg<<<QBLKS, 256, 0, stream>>>(q_xyz, s_xyz, ft, out);
    } else {
        ballgroup_fb<<<QBLKS, 256, 0, stream>>>(q_xyz, s_xyz, feat, out);
    }
}